// Round 2
// baseline (479.843 us; speedup 1.0000x reference)
//
#include <hip/hip_runtime.h>
#include <hip/hip_bf16.h>
#include <stdint.h>

typedef __bf16 bf16;
typedef __bf16 bf16x8 __attribute__((ext_vector_type(8)));
typedef __bf16 bf16x4 __attribute__((ext_vector_type(4)));
typedef float  f32x4  __attribute__((ext_vector_type(4)));

static __device__ __forceinline__ void gll16(const void* g, void* l) {
    __builtin_amdgcn_global_load_lds((__attribute__((address_space(1))) void*)(void*)g,
                                     (__attribute__((address_space(3))) void*)l, 16, 0, 0);
}

// ---------------- fp32 -> bf16 convert ----------------
__global__ __launch_bounds__(256) void cvt_f32_bf16(const float* __restrict__ in,
                                                    bf16* __restrict__ out, int n4) {
    int i = blockIdx.x * 256 + threadIdx.x;
    const int stride = gridDim.x * 256;
    for (; i < n4; i += stride) {
        f32x4 v = *(const f32x4*)(in + (size_t)i * 4);
        bf16x4 o;
        o[0] = (bf16)v[0]; o[1] = (bf16)v[1]; o[2] = (bf16)v[2]; o[3] = (bf16)v[3];
        *(bf16x4*)(out + (size_t)i * 4) = o;
    }
}

// ---------------- QKV GEMM: Y[16384][3072] = act(X @ W^T + b) ----------------
// X: 16384x1024 bf16, W: 3072x1024 bf16 (rows 0..2047 = w_qk, 2048..3071 = w_v)
// cols < 2048 get elu(x)+1.
__global__ __launch_bounds__(256) void gemm_qkv(const bf16* __restrict__ X,
                                                const bf16* __restrict__ W,
                                                const float* __restrict__ b_qk,
                                                const float* __restrict__ b_v,
                                                bf16* __restrict__ Y) {
    __shared__ bf16 sm[8192];          // A tile [128][32] at 0, B tile [128][32] at +4096 elems
    const int t    = threadIdx.x;
    const int lane = t & 63;
    const int wv   = t >> 6;
    const int wr   = wv >> 1, wc = wv & 1;
    const int m0   = blockIdx.x * 128;
    const int n0   = blockIdx.y * 128;

    // staging: thread t loads 16B; row = t/4 (+64), k-offset = (t&3)*8
    const int sr = t >> 2;
    const int sc = (t & 3) * 8;
    const bf16* gA0 = X + (size_t)(m0 + sr) * 1024 + sc;
    const bf16* gA1 = gA0 + (size_t)64 * 1024;
    const bf16* gB0 = W + (size_t)(n0 + sr) * 1024 + sc;
    const bf16* gB1 = gB0 + (size_t)64 * 1024;
    char* smb = (char*)sm;
    char* lA0 = smb + t * 16;
    char* lA1 = smb + 4096  + t * 16;
    char* lB0 = smb + 8192  + t * 16;
    char* lB1 = smb + 12288 + t * 16;

    const bf16* As = sm;
    const bf16* Bs = sm + 4096;
    const int fr = lane & 15;
    const int fk = (lane >> 4) * 8;

    f32x4 acc[4][4] = {};

    for (int k0 = 0; k0 < 1024; k0 += 32) {
        gll16(gA0 + k0, lA0);
        gll16(gA1 + k0, lA1);
        gll16(gB0 + k0, lB0);
        gll16(gB1 + k0, lB1);
        __syncthreads();   // drains vmcnt before barrier (compiler-enforced)
        bf16x8 aF[4], bF[4];
#pragma unroll
        for (int mi = 0; mi < 4; ++mi)
            aF[mi] = *(const bf16x8*)(As + (wr * 64 + mi * 16 + fr) * 32 + fk);
#pragma unroll
        for (int ni = 0; ni < 4; ++ni)
            bF[ni] = *(const bf16x8*)(Bs + (wc * 64 + ni * 16 + fr) * 32 + fk);
#pragma unroll
        for (int mi = 0; mi < 4; ++mi)
#pragma unroll
            for (int ni = 0; ni < 4; ++ni)
                acc[mi][ni] = __builtin_amdgcn_mfma_f32_16x16x32_bf16(aF[mi], bF[ni], acc[mi][ni], 0, 0, 0);
        __syncthreads();
    }

    const bool isqk = (n0 < 2048);
#pragma unroll
    for (int ni = 0; ni < 4; ++ni) {
        const int col = n0 + wc * 64 + ni * 16 + (lane & 15);
        const float bv = isqk ? b_qk[col] : b_v[col - 2048];
#pragma unroll
        for (int mi = 0; mi < 4; ++mi) {
            const int row0 = m0 + wr * 64 + mi * 16 + (lane >> 4) * 4;
#pragma unroll
            for (int j = 0; j < 4; ++j) {
                float vo = acc[mi][ni][j] + bv;
                if (isqk) vo = vo > 0.f ? vo + 1.f : expf(vo);   // elu(x)+1
                Y[(size_t)(row0 + j) * 3072 + col] = (bf16)vo;
            }
        }
    }
}

// ---------------- LePE: out[l,d] = a[l,d] + conv_bh[d][l] ----------------
// a_slab[l][d] = Y[(b*4096+l)*3072 + isK*1024 + h*64 + d]
// conv_bh[d][l] = w0*ar[d][l-1] + w1*ar[d][l] + w2*ar[d][l+1] + bl[d],
//   ar[d][p] = a_slab[d*64 + p/64][p%64], zero-pad at p<0 / p>4095.
// block = (bh, m): computes l in [64m, 64m+64), all 64 d.
__global__ __launch_bounds__(256) void lepe(const bf16* __restrict__ Y,
                                            const float* __restrict__ wl,
                                            const float* __restrict__ bl,
                                            bf16* __restrict__ qf,
                                            bf16* __restrict__ kf) {
    const int bx = blockIdx.x;
    const int bh = bx >> 6, m = bx & 63;
    const int b = bh >> 4, h = bh & 15;
    const int isK = blockIdx.y;
    const bf16* slab = Y + (size_t)(b * 4096) * 3072 + isK * 1024 + h * 64;
    bf16* outp = (isK ? kf : qf) + (size_t)(b * 4096) * 1024 + h * 64;

    __shared__ bf16  Gs[64][72];
    __shared__ float Cs[64][65];
    __shared__ float ep[64], en[64];
    const int t = threadIdx.x;
    {   // gather tile: G[d][j] = a_slab[d*64+m][j]
        const int d = t >> 2, c0 = (t & 3) * 16;
        const bf16* src = slab + (size_t)(d * 64 + m) * 3072 + c0;
        *(bf16x8*)&Gs[d][c0]     = *(const bf16x8*)src;
        *(bf16x8*)&Gs[d][c0 + 8] = *(const bf16x8*)(src + 8);
    }
    if (t < 64) {
        const int d = t;
        ep[d] = (m > 0)  ? (float)slab[(size_t)(d * 64 + m - 1) * 3072 + 63] : 0.f;
        en[d] = (m < 63) ? (float)slab[(size_t)(d * 64 + m + 1) * 3072 + 0]  : 0.f;
    }
    __syncthreads();
    {   // depthwise conv along j
        const int d = t >> 2, j0 = (t & 3) * 16;
        const float w0 = wl[d * 3], w1 = wl[d * 3 + 1], w2 = wl[d * 3 + 2], bb = bl[d];
#pragma unroll
        for (int jj = 0; jj < 16; ++jj) {
            const int j = j0 + jj;
            const float left  = (j == 0)  ? ep[d] : (float)Gs[d][j - 1];
            const float mid   = (float)Gs[d][j];
            const float right = (j == 63) ? en[d] : (float)Gs[d][j + 1];
            Cs[d][j] = w0 * left + w1 * mid + w2 * right + bb;
        }
    }
    __syncthreads();
    {   // add + write: out[64m+j][d] = a[64m+j][d] + Cs[d][j]
        const int j = t >> 2, c0 = (t & 3) * 16;
        const size_t l = (size_t)(m * 64 + j);
        const bf16* arow = slab + l * 3072 + c0;
        bf16* orow = outp + l * 1024 + c0;
        bf16x8 a0 = *(const bf16x8*)arow;
        bf16x8 a1 = *(const bf16x8*)(arow + 8);
        bf16x8 o0, o1;
#pragma unroll
        for (int i = 0; i < 8; ++i) {
            o0[i] = (bf16)((float)a0[i] + Cs[c0 + i][j]);
            o1[i] = (bf16)((float)a1[i] + Cs[c0 + 8 + i][j]);
        }
        *(bf16x8*)orow = o0;
        *(bf16x8*)(orow + 8) = o1;
    }
}

// ---------------- kv/ksum partials: per (bh, chunk of 1024 l) ----------------
__global__ __launch_bounds__(256) void kv_partial(const bf16* __restrict__ kf,
                                                  const bf16* __restrict__ Y,
                                                  float* __restrict__ kvp,
                                                  float* __restrict__ ksp) {
    const int bh = blockIdx.x, ch = blockIdx.y;
    const int b = bh >> 4, h = bh & 15;
    const bf16* K = kf + (size_t)(b * 4096) * 1024 + h * 64;
    const bf16* V = Y + (size_t)(b * 4096) * 3072 + 2048 + h * 64;
    __shared__ float Ks[16][64];
    __shared__ float Vs[16][64];
    const int t = threadIdx.x;
    const int d = t >> 2, e0 = (t & 3) * 16;
    float acc[16] = {};
    float ks = 0.f;
    const int l0 = ch * 1024;
    for (int base = l0; base < l0 + 1024; base += 16) {
        __syncthreads();
        if (t < 128) {
            const int r = t >> 3, s = (t & 7) * 8;
            bf16x8 v = *(const bf16x8*)(K + (size_t)(base + r) * 1024 + s);
#pragma unroll
            for (int i = 0; i < 8; ++i) Ks[r][s + i] = (float)v[i];
        } else {
            const int tt = t - 128, r = tt >> 3, s = (tt & 7) * 8;
            bf16x8 v = *(const bf16x8*)(V + (size_t)(base + r) * 3072 + s);
#pragma unroll
            for (int i = 0; i < 8; ++i) Vs[r][s + i] = (float)v[i];
        }
        __syncthreads();
#pragma unroll
        for (int ll = 0; ll < 16; ++ll) {
            const float kd = Ks[ll][d];
            ks += kd;
            const float* vr = &Vs[ll][e0];
#pragma unroll
            for (int e = 0; e < 16; ++e) acc[e] += kd * vr[e];
        }
    }
    float* o = kvp + (((size_t)ch * 64 + bh) * 64 + d) * 64 + e0;
#pragma unroll
    for (int e = 0; e < 16; ++e) o[e] = acc[e];
    if (e0 == 0) ksp[(size_t)ch * 4096 + bh * 64 + d] = ks;
}

// ---------------- out[l,e] = (q . kv_acc[:,e]) / (q . ksum + L*1e-6) ----------------
// d_out is FLOAT32 (reference output dtype is fp32).
__global__ __launch_bounds__(256) void out_kernel(const bf16* __restrict__ qf,
                                                  const float* __restrict__ kvp,
                                                  const float* __restrict__ ksp,
                                                  float* __restrict__ out) {
    const int bh = blockIdx.x;
    const int b = bh >> 4, h = bh & 15;
    __shared__ float kvS[4096];
    __shared__ float ksS[64];
    const int t = threadIdx.x;
    const float* kp = kvp + (size_t)bh * 4096;
#pragma unroll
    for (int i = 0; i < 4; ++i) {
        const int idx = i * 1024 + t * 4;
        f32x4 v = *(const f32x4*)(kp + idx);
        v = v + *(const f32x4*)(kp + 262144 + idx);
        v = v + *(const f32x4*)(kp + 524288 + idx);
        v = v + *(const f32x4*)(kp + 786432 + idx);
        *(f32x4*)(kvS + idx) = v;
    }
    if (t < 64) {
        ksS[t] = ksp[bh * 64 + t] + ksp[4096 + bh * 64 + t] +
                 ksp[8192 + bh * 64 + t] + ksp[12288 + bh * 64 + t];
    }
    __syncthreads();

    const int l = blockIdx.y * 256 + t;
    const size_t row = (size_t)(b * 4096 + l);
    const bf16* qrow = qf + row * 1024 + h * 64;
    bf16x8 qv[8];
#pragma unroll
    for (int i = 0; i < 8; ++i) qv[i] = *(const bf16x8*)(qrow + i * 8);

    float s = 0.f;
#pragma unroll
    for (int i = 0; i < 8; ++i)
#pragma unroll
        for (int j = 0; j < 8; ++j) s += (float)qv[i][j] * ksS[i * 8 + j];
    const float inv = 1.0f / (s + 0.004096f);   // + L*1e-6 (z-fold; kv /L cancels)

    f32x4 acc[16] = {};
#pragma unroll
    for (int i = 0; i < 8; ++i) {
#pragma unroll
        for (int j = 0; j < 8; ++j) {
            const float qd = (float)qv[i][j];
            const float* kr = kvS + (i * 8 + j) * 64;
#pragma unroll
            for (int e4 = 0; e4 < 16; ++e4)
                acc[e4] += qd * (*(const f32x4*)(kr + e4 * 4));
        }
    }
    float* orow = out + row * 1024 + h * 64;
#pragma unroll
    for (int e4 = 0; e4 < 16; ++e4) {
        *(f32x4*)(orow + e4 * 4) = acc[e4] * inv;
    }
}

extern "C" void kernel_launch(void* const* d_in, const int* in_sizes, int n_in,
                              void* d_out, int out_size, void* d_ws, size_t ws_size,
                              hipStream_t stream) {
    const float* x      = (const float*)d_in[0];
    const float* w_qk   = (const float*)d_in[1];
    const float* b_qk   = (const float*)d_in[2];
    const float* w_v    = (const float*)d_in[3];
    const float* b_v    = (const float*)d_in[4];
    const float* w_lepe = (const float*)d_in[5];
    const float* b_lepe = (const float*)d_in[6];

    char* ws = (char*)d_ws;
    bf16*  Y   = (bf16*)ws;                       // 16384*3072*2        = 100,663,296
    bf16*  xb  = (bf16*)(ws + 100663296);         // 33,554,432 (reused as qf after GEMM)
    bf16*  Wb  = (bf16*)(ws + 134217728);         // 33,554,432 (reused as kf after GEMM)
    float* kvp = (float*)(ws + 167772160);        // 4 chunks * 64 bh * 64*64 f32 = 4,194,304
    float* ksp = (float*)(ws + 171966464);        // 4 * 64 * 64 f32 = 65,536
    bf16* qf = xb;
    bf16* kf = Wb;

    cvt_f32_bf16<<<2048, 256, 0, stream>>>(x, xb, 16777216 / 4);
    cvt_f32_bf16<<<512,  256, 0, stream>>>(w_qk, Wb, 2097152 / 4);
    cvt_f32_bf16<<<256,  256, 0, stream>>>(w_v, Wb + 2097152, 1048576 / 4);
    gemm_qkv<<<dim3(128, 24), 256, 0, stream>>>(xb, Wb, b_qk, b_v, Y);
    lepe<<<dim3(4096, 2), 256, 0, stream>>>(Y, w_lepe, b_lepe, qf, kf);
    kv_partial<<<dim3(64, 4), 256, 0, stream>>>(kf, Y, kvp, ksp);
    out_kernel<<<dim3(64, 16), 256, 0, stream>>>(qf, kvp, ksp, (float*)d_out);
}

// Round 4
// 423.512 us; speedup vs baseline: 1.1330x; 1.1330x over previous
//
#include <hip/hip_runtime.h>
#include <hip/hip_bf16.h>
#include <stdint.h>

typedef __bf16 bf16;
typedef __bf16 bf16x8 __attribute__((ext_vector_type(8)));
typedef __bf16 bf16x4 __attribute__((ext_vector_type(4)));
typedef float  f32x4  __attribute__((ext_vector_type(4)));

static __device__ __forceinline__ void gll16(const void* g, void* l) {
    __builtin_amdgcn_global_load_lds((__attribute__((address_space(1))) void*)(void*)g,
                                     (__attribute__((address_space(3))) void*)l, 16, 0, 0);
}

// ---------------- fp32 -> bf16 convert ----------------
__global__ __launch_bounds__(256) void cvt_f32_bf16(const float* __restrict__ in,
                                                    bf16* __restrict__ out, int n4) {
    int i = blockIdx.x * 256 + threadIdx.x;
    const int stride = gridDim.x * 256;
    for (; i < n4; i += stride) {
        f32x4 v = *(const f32x4*)(in + (size_t)i * 4);
        bf16x4 o;
        o[0] = (bf16)v[0]; o[1] = (bf16)v[1]; o[2] = (bf16)v[2]; o[3] = (bf16)v[3];
        *(bf16x4*)(out + (size_t)i * 4) = o;
    }
}

// ---------------- QKV GEMM: Y[16384][3072] = act(X @ W^T + b) ----------------
__global__ __launch_bounds__(256) void gemm_qkv(const bf16* __restrict__ X,
                                                const bf16* __restrict__ W,
                                                const float* __restrict__ b_qk,
                                                const float* __restrict__ b_v,
                                                bf16* __restrict__ Y) {
    __shared__ bf16 sm[8192];
    const int t    = threadIdx.x;
    const int lane = t & 63;
    const int wv   = t >> 6;
    const int wr   = wv >> 1, wc = wv & 1;
    const int m0   = blockIdx.x * 128;
    const int n0   = blockIdx.y * 128;

    const int sr = t >> 2;
    const int sc = (t & 3) * 8;
    const bf16* gA0 = X + (size_t)(m0 + sr) * 1024 + sc;
    const bf16* gA1 = gA0 + (size_t)64 * 1024;
    const bf16* gB0 = W + (size_t)(n0 + sr) * 1024 + sc;
    const bf16* gB1 = gB0 + (size_t)64 * 1024;
    char* smb = (char*)sm;
    char* lA0 = smb + t * 16;
    char* lA1 = smb + 4096  + t * 16;
    char* lB0 = smb + 8192  + t * 16;
    char* lB1 = smb + 12288 + t * 16;

    const bf16* As = sm;
    const bf16* Bs = sm + 4096;
    const int fr = lane & 15;
    const int fk = (lane >> 4) * 8;

    f32x4 acc[4][4] = {};

    for (int k0 = 0; k0 < 1024; k0 += 32) {
        gll16(gA0 + k0, lA0);
        gll16(gA1 + k0, lA1);
        gll16(gB0 + k0, lB0);
        gll16(gB1 + k0, lB1);
        __syncthreads();
        bf16x8 aF[4], bF[4];
#pragma unroll
        for (int mi = 0; mi < 4; ++mi)
            aF[mi] = *(const bf16x8*)(As + (wr * 64 + mi * 16 + fr) * 32 + fk);
#pragma unroll
        for (int ni = 0; ni < 4; ++ni)
            bF[ni] = *(const bf16x8*)(Bs + (wc * 64 + ni * 16 + fr) * 32 + fk);
#pragma unroll
        for (int mi = 0; mi < 4; ++mi)
#pragma unroll
            for (int ni = 0; ni < 4; ++ni)
                acc[mi][ni] = __builtin_amdgcn_mfma_f32_16x16x32_bf16(aF[mi], bF[ni], acc[mi][ni], 0, 0, 0);
        __syncthreads();
    }

    const bool isqk = (n0 < 2048);
#pragma unroll
    for (int ni = 0; ni < 4; ++ni) {
        const int col = n0 + wc * 64 + ni * 16 + (lane & 15);
        const float bv = isqk ? b_qk[col] : b_v[col - 2048];
#pragma unroll
        for (int mi = 0; mi < 4; ++mi) {
            const int row0 = m0 + wr * 64 + mi * 16 + (lane >> 4) * 4;
#pragma unroll
            for (int j = 0; j < 4; ++j) {
                float vo = acc[mi][ni][j] + bv;
                if (isqk) vo = vo > 0.f ? vo + 1.f : expf(vo);   // elu(x)+1
                Y[(size_t)(row0 + j) * 3072 + col] = (bf16)vo;
            }
        }
    }
}

// ---------------- LePE (unchanged) ----------------
__global__ __launch_bounds__(256) void lepe(const bf16* __restrict__ Y,
                                            const float* __restrict__ wl,
                                            const float* __restrict__ bl,
                                            bf16* __restrict__ qf,
                                            bf16* __restrict__ kf) {
    const int bx = blockIdx.x;
    const int bh = bx >> 6, m = bx & 63;
    const int b = bh >> 4, h = bh & 15;
    const int isK = blockIdx.y;
    const bf16* slab = Y + (size_t)(b * 4096) * 3072 + isK * 1024 + h * 64;
    bf16* outp = (isK ? kf : qf) + (size_t)(b * 4096) * 1024 + h * 64;

    __shared__ bf16  Gs[64][72];
    __shared__ float Cs[64][65];
    __shared__ float ep[64], en[64];
    const int t = threadIdx.x;
    {
        const int d = t >> 2, c0 = (t & 3) * 16;
        const bf16* src = slab + (size_t)(d * 64 + m) * 3072 + c0;
        *(bf16x8*)&Gs[d][c0]     = *(const bf16x8*)src;
        *(bf16x8*)&Gs[d][c0 + 8] = *(const bf16x8*)(src + 8);
    }
    if (t < 64) {
        const int d = t;
        ep[d] = (m > 0)  ? (float)slab[(size_t)(d * 64 + m - 1) * 3072 + 63] : 0.f;
        en[d] = (m < 63) ? (float)slab[(size_t)(d * 64 + m + 1) * 3072 + 0]  : 0.f;
    }
    __syncthreads();
    {
        const int d = t >> 2, j0 = (t & 3) * 16;
        const float w0 = wl[d * 3], w1 = wl[d * 3 + 1], w2 = wl[d * 3 + 2], bb = bl[d];
#pragma unroll
        for (int jj = 0; jj < 16; ++jj) {
            const int j = j0 + jj;
            const float left  = (j == 0)  ? ep[d] : (float)Gs[d][j - 1];
            const float mid   = (float)Gs[d][j];
            const float right = (j == 63) ? en[d] : (float)Gs[d][j + 1];
            Cs[d][j] = w0 * left + w1 * mid + w2 * right + bb;
        }
    }
    __syncthreads();
    {
        const int j = t >> 2, c0 = (t & 3) * 16;
        const size_t l = (size_t)(m * 64 + j);
        const bf16* arow = slab + l * 3072 + c0;
        bf16* orow = outp + l * 1024 + c0;
        bf16x8 a0 = *(const bf16x8*)arow;
        bf16x8 a1 = *(const bf16x8*)(arow + 8);
        bf16x8 o0, o1;
#pragma unroll
        for (int i = 0; i < 8; ++i) {
            o0[i] = (bf16)((float)a0[i] + Cs[c0 + i][j]);
            o1[i] = (bf16)((float)a1[i] + Cs[c0 + 8 + i][j]);
        }
        *(bf16x8*)orow = o0;
        *(bf16x8*)(orow + 8) = o1;
    }
}

// ---------------- kv/ksum partials, register-blocked ----------------
// Per lane: 8d x 8e accumulator; 64-l stages split across 4 waves (16 l each).
// Cross-wave reduce in LDS -> 4 partials per (d,e), same kvp/ksp layout as before.
__global__ __launch_bounds__(256) void kv_partial(const bf16* __restrict__ kf,
                                                  const bf16* __restrict__ Y,
                                                  float* __restrict__ kvp,
                                                  float* __restrict__ ksp) {
    const int bh = blockIdx.x, ch = blockIdx.y;
    const int b = bh >> 4, h = bh & 15;
    const bf16* K = kf + (size_t)(b * 4096) * 1024 + h * 64;
    const bf16* V = Y + (size_t)(b * 4096) * 3072 + 2048 + h * 64;

    __shared__ float SM[64 * 68 * 2 + 4 * 64];   // Ks | Vs | ksr
#define KS(r, c) SM[(r) * 68 + (c)]
#define VS(r, c) SM[4352 + (r) * 68 + (c)]
    float* ksr = SM + 8704;

    const int t = threadIdx.x;
    const int lane = t & 63;
    const int w = t >> 6;
    const int dg = lane >> 3, eg = lane & 7;

    f32x4 acc[8][2] = {};
    f32x4 ks0 = {}, ks1 = {};

    const int j = t >> 2, c0 = (t & 3) * 16;
    const int l0 = ch * 1024;
    const bf16* Kp = K + (size_t)(l0 + j) * 1024 + c0;
    const bf16* Vp = V + (size_t)(l0 + j) * 3072 + c0;
    bf16x8 k0 = *(const bf16x8*)Kp, k1 = *(const bf16x8*)(Kp + 8);
    bf16x8 v0 = *(const bf16x8*)Vp, v1 = *(const bf16x8*)(Vp + 8);

    for (int s = 0; s < 16; ++s) {
        __syncthreads();
        {   // stage (f32)
            f32x4 a, bx, c, d2;
#pragma unroll
            for (int i = 0; i < 4; ++i) { a[i] = (float)k0[i]; bx[i] = (float)k0[4 + i]; }
            *(f32x4*)&KS(j, c0) = a;  *(f32x4*)&KS(j, c0 + 4) = bx;
#pragma unroll
            for (int i = 0; i < 4; ++i) { c[i] = (float)k1[i]; d2[i] = (float)k1[4 + i]; }
            *(f32x4*)&KS(j, c0 + 8) = c; *(f32x4*)&KS(j, c0 + 12) = d2;
#pragma unroll
            for (int i = 0; i < 4; ++i) { a[i] = (float)v0[i]; bx[i] = (float)v0[4 + i]; }
            *(f32x4*)&VS(j, c0) = a;  *(f32x4*)&VS(j, c0 + 4) = bx;
#pragma unroll
            for (int i = 0; i < 4; ++i) { c[i] = (float)v1[i]; d2[i] = (float)v1[4 + i]; }
            *(f32x4*)&VS(j, c0 + 8) = c; *(f32x4*)&VS(j, c0 + 12) = d2;
        }
        __syncthreads();
        if (s < 15) {   // prefetch next stage (hides HBM under compute)
            Kp += (size_t)64 * 1024; Vp += (size_t)64 * 3072;
            k0 = *(const bf16x8*)Kp; k1 = *(const bf16x8*)(Kp + 8);
            v0 = *(const bf16x8*)Vp; v1 = *(const bf16x8*)(Vp + 8);
        }
#pragma unroll
        for (int jj = 0; jj < 16; ++jj) {
            const int l = w * 16 + jj;
            f32x4 ka = *(const f32x4*)&KS(l, dg * 8);
            f32x4 kb = *(const f32x4*)&KS(l, dg * 8 + 4);
            f32x4 va = *(const f32x4*)&VS(l, eg * 8);
            f32x4 vb = *(const f32x4*)&VS(l, eg * 8 + 4);
            ks0 += ka; ks1 += kb;
#pragma unroll
            for (int i = 0; i < 4; ++i) {
                acc[i][0] += ka[i] * va;     acc[i][1] += ka[i] * vb;
                acc[4 + i][0] += kb[i] * va; acc[4 + i][1] += kb[i] * vb;
            }
        }
    }

    __syncthreads();   // all waves done with Ks/Vs; alias as reduce scratch
    if (eg == 0) {
#pragma unroll
        for (int i = 0; i < 4; ++i) {
            ksr[w * 64 + dg * 8 + i]     = ks0[i];
            ksr[w * 64 + dg * 8 + 4 + i] = ks1[i];
        }
    }
    if (w == 1 || w == 3) {
        float* buf = SM + (w >> 1) * 4352 + lane * 68;
#pragma unroll
        for (int i = 0; i < 8; ++i) {
            *(f32x4*)(buf + i * 8) = acc[i][0];
            *(f32x4*)(buf + i * 8 + 4) = acc[i][1];
        }
    }
    __syncthreads();
    if (w == 0 || w == 2) {
        float* buf = SM + (w >> 1) * 4352 + lane * 68;
#pragma unroll
        for (int i = 0; i < 8; ++i) {
            acc[i][0] += *(const f32x4*)(buf + i * 8);
            acc[i][1] += *(const f32x4*)(buf + i * 8 + 4);
        }
    }
    __syncthreads();
    if (w == 2) {
        float* buf = SM + lane * 68;
#pragma unroll
        for (int i = 0; i < 8; ++i) {
            *(f32x4*)(buf + i * 8) = acc[i][0];
            *(f32x4*)(buf + i * 8 + 4) = acc[i][1];
        }
    }
    __syncthreads();
    if (w == 0) {
        float* buf = SM + lane * 68;
#pragma unroll
        for (int i = 0; i < 8; ++i) {
            acc[i][0] += *(const f32x4*)(buf + i * 8);
            acc[i][1] += *(const f32x4*)(buf + i * 8 + 4);
        }
        float* o = kvp + (((size_t)ch * 64 + bh) * 64 + dg * 8) * 64 + eg * 8;
#pragma unroll
        for (int i = 0; i < 8; ++i) {
            *(f32x4*)(o + (size_t)i * 64)     = acc[i][0];
            *(f32x4*)(o + (size_t)i * 64 + 4) = acc[i][1];
        }
        if (eg == 0) {
#pragma unroll
            for (int i = 0; i < 8; ++i) {
                const int d = dg * 8 + i;
                ksp[(size_t)ch * 4096 + bh * 64 + d] =
                    ksr[d] + ksr[64 + d] + ksr[128 + d] + ksr[192 + d];
            }
        }
    }
#undef KS
#undef VS
}

// ---------------- out, register-blocked: 4 rows x 16 e per thread ----------------
__global__ __launch_bounds__(256) void out_kernel(const bf16* __restrict__ qf,
                                                  const float* __restrict__ kvp,
                                                  const float* __restrict__ ksp,
                                                  float* __restrict__ out) {
    const int bh = blockIdx.x;
    const int b = bh >> 4, h = bh & 15;
    __shared__ float kvS[4096];
    __shared__ float ksS[64];
    const int t = threadIdx.x;
    const float* kp = kvp + (size_t)bh * 4096;
#pragma unroll
    for (int i = 0; i < 4; ++i) {
        const int idx = i * 1024 + t * 4;
        f32x4 v = *(const f32x4*)(kp + idx);
        v = v + *(const f32x4*)(kp + 262144 + idx);
        v = v + *(const f32x4*)(kp + 524288 + idx);
        v = v + *(const f32x4*)(kp + 786432 + idx);
        *(f32x4*)(kvS + idx) = v;
    }
    if (t < 64) {
        ksS[t] = ksp[bh * 64 + t] + ksp[4096 + bh * 64 + t] +
                 ksp[8192 + bh * 64 + t] + ksp[12288 + bh * 64 + t];
    }
    __syncthreads();

    const int rg = t >> 2, eg = t & 3, e0 = eg * 16;
    const int r0 = blockIdx.y * 256 + rg * 4;
    const bf16* qbase = qf + (size_t)(b * 4096 + r0) * 1024 + h * 64;

    bf16x8 qv[4][8];
#pragma unroll
    for (int i = 0; i < 4; ++i)
#pragma unroll
        for (int s = 0; s < 8; ++s)
            qv[i][s] = *(const bf16x8*)(qbase + (size_t)i * 1024 + s * 8);

    float inv[4];
#pragma unroll
    for (int i = 0; i < 4; ++i) {
        float s = 0.f;
#pragma unroll
        for (int ss = 0; ss < 8; ++ss)
#pragma unroll
            for (int jj = 0; jj < 8; ++jj)
                s += (float)qv[i][ss][jj] * ksS[ss * 8 + jj];
        inv[i] = 1.0f / (s + 0.004096f);   // + L*1e-6 (kv /L folded)
    }

    f32x4 acc[4][4] = {};
#pragma unroll
    for (int d = 0; d < 64; ++d) {
        const float* kr = kvS + d * 64 + e0;
        f32x4 k0 = *(const f32x4*)kr;
        f32x4 k1 = *(const f32x4*)(kr + 4);
        f32x4 k2 = *(const f32x4*)(kr + 8);
        f32x4 k3 = *(const f32x4*)(kr + 12);
#pragma unroll
        for (int i = 0; i < 4; ++i) {
            const float qd = (float)qv[i][d >> 3][d & 7];
            acc[i][0] += qd * k0;
            acc[i][1] += qd * k1;
            acc[i][2] += qd * k2;
            acc[i][3] += qd * k3;
        }
    }
#pragma unroll
    for (int i = 0; i < 4; ++i) {
        float* orow = out + (size_t)(b * 4096 + r0 + i) * 1024 + h * 64 + e0;
#pragma unroll
        for (int q = 0; q < 4; ++q)
            *(f32x4*)(orow + q * 4) = acc[i][q] * inv[i];
    }
}

extern "C" void kernel_launch(void* const* d_in, const int* in_sizes, int n_in,
                              void* d_out, int out_size, void* d_ws, size_t ws_size,
                              hipStream_t stream) {
    const float* x      = (const float*)d_in[0];
    const float* w_qk   = (const float*)d_in[1];
    const float* b_qk   = (const float*)d_in[2];
    const float* w_v    = (const float*)d_in[3];
    const float* b_v    = (const float*)d_in[4];
    const float* w_lepe = (const float*)d_in[5];
    const float* b_lepe = (const float*)d_in[6];

    char* ws = (char*)d_ws;
    bf16*  Y   = (bf16*)ws;                       // 100,663,296
    bf16*  xb  = (bf16*)(ws + 100663296);         // 33,554,432 (qf after GEMM)
    bf16*  Wb  = (bf16*)(ws + 134217728);         // 33,554,432 (kf after GEMM)
    float* kvp = (float*)(ws + 167772160);        // 4 * 64 * 64 * 64 f32 = 4,194,304
    float* ksp = (float*)(ws + 171966464);        // 4 * 64 * 64 f32 = 65,536
    bf16* qf = xb;
    bf16* kf = Wb;

    cvt_f32_bf16<<<2048, 256, 0, stream>>>(x, xb, 16777216 / 4);
    cvt_f32_bf16<<<512,  256, 0, stream>>>(w_qk, Wb, 2097152 / 4);
    cvt_f32_bf16<<<256,  256, 0, stream>>>(w_v, Wb + 2097152, 1048576 / 4);
    gemm_qkv<<<dim3(128, 24), 256, 0, stream>>>(xb, Wb, b_qk, b_v, Y);
    lepe<<<dim3(4096, 2), 256, 0, stream>>>(Y, w_lepe, b_lepe, qf, kf);
    kv_partial<<<dim3(64, 4), 256, 0, stream>>>(kf, Y, kvp, ksp);
    out_kernel<<<dim3(64, 16), 256, 0, stream>>>(qf, kvp, ksp, (float*)d_out);
}

// Round 5
// 414.282 us; speedup vs baseline: 1.1583x; 1.0223x over previous
//
#include <hip/hip_runtime.h>
#include <hip/hip_bf16.h>
#include <stdint.h>

typedef __bf16 bf16;
typedef __bf16 bf16x8 __attribute__((ext_vector_type(8)));
typedef __bf16 bf16x4 __attribute__((ext_vector_type(4)));
typedef float  f32x4  __attribute__((ext_vector_type(4)));

static __device__ __forceinline__ void gll16(const void* g, void* l) {
    __builtin_amdgcn_global_load_lds((__attribute__((address_space(1))) void*)(void*)g,
                                     (__attribute__((address_space(3))) void*)l, 16, 0, 0);
}

// ---------------- fp32 -> bf16 convert ----------------
__global__ __launch_bounds__(256) void cvt_f32_bf16(const float* __restrict__ in,
                                                    bf16* __restrict__ out, int n4) {
    int i = blockIdx.x * 256 + threadIdx.x;
    const int stride = gridDim.x * 256;
    for (; i < n4; i += stride) {
        f32x4 v = *(const f32x4*)(in + (size_t)i * 4);
        bf16x4 o;
        o[0] = (bf16)v[0]; o[1] = (bf16)v[1]; o[2] = (bf16)v[2]; o[3] = (bf16)v[3];
        *(bf16x4*)(out + (size_t)i * 4) = o;
    }
}

// ---------------- QKV GEMM, 256x256 tile, BK=64, 8-wave 8-phase ----------------
// Y[16384][3072] = act(X @ W^T + b). LDS: A dbuf 2x32KB @0, B dbuf 2x32KB @64KB.
// Swizzle: 128B rows, 16B slots, slot ^= (row&7)  (T2; source-side pre-swizzle).
// Waits: vmcnt(4) at phase-1 end (A-hi of cur tile), vmcnt(2) at phase-3 end
// (B + A-lo of next tile). Never 0 in main loop (T4).
#define WAITV(n) asm volatile("s_waitcnt vmcnt(" #n ")" ::: "memory")
#define STA(s_, half, pass, k0_) \
    gll16(Xs + (size_t)((half) * 128 + (pass) * 64) * 1024 + (k0_), \
          lds + (s_) * 32768 + (half) * 16384 + (pass) * 8192 + t * 16)
#define STB(s_, half, pass, k0_) \
    gll16(Ws + (size_t)((half) * 128 + (pass) * 64) * 1024 + (k0_), \
          lds + 65536 + (s_) * 32768 + (half) * 16384 + (pass) * 8192 + t * 16)

__global__ __launch_bounds__(512, 2) void gemm_qkv(const bf16* __restrict__ X,
                                                   const bf16* __restrict__ W,
                                                   const float* __restrict__ b_qk,
                                                   const float* __restrict__ b_v,
                                                   bf16* __restrict__ Y) {
    __shared__ char lds[131072];
    const int t    = threadIdx.x;
    const int lane = t & 63;
    const int wid  = t >> 6;
    const int wm   = wid >> 2, wn = wid & 3;

    // XCD-aware bijective swizzle (768 blocks, 768%8==0)
    const int bid = blockIdx.x;
    const int wg  = (bid & 7) * 96 + (bid >> 3);
    const int m0  = (wg & 63) * 256;
    const int n0  = (wg >> 6) * 256;

    // staging source: row = t>>3 (+pass*64 +half*128), col pre-swizzled
    const int scol = (((t & 7) ^ ((t >> 3) & 7)) * 8);
    const bf16* Xs = X + (size_t)(m0 + (t >> 3)) * 1024 + scol;
    const bf16* Ws = W + (size_t)(n0 + (t >> 3)) * 1024 + scol;

    // fragment read addressing
    const int fr = lane & 15;
    const int l7 = lane & 7;
    const int ax0 = (((lane >> 4) + 0) ^ l7) << 4;   // kk=0
    const int ax1 = (((lane >> 4) + 4) ^ l7) << 4;   // kk=1
    const int baseA = wm * 16384 + fr * 128;
    const int baseB = 65536 + (wn >> 1) * 16384 + ((wn & 1) * 64 + fr) * 128;

    f32x4 acc[8][4] = {};
    bf16x8 bF[4][2];

    // prologue: stage K-tile 0 into slot 0 (order: B0,B1,A-lo,A-hi)
    STB(0, 0, 0, 0); STB(0, 0, 1, 0); STB(0, 1, 0, 0); STB(0, 1, 1, 0);
    STA(0, 0, 0, 0); STA(0, 1, 0, 0); STA(0, 0, 1, 0); STA(0, 1, 1, 0);
    WAITV(2);
    __builtin_amdgcn_s_barrier();

    for (int j = 0; j < 16; ++j) {
        const int s  = j & 1;
        const int sn = s ^ 1;
        const int kn = (j + 1) << 6;
        const bool st = j < 15;
        const int sA = s * 32768 + baseA;
        const int sB = s * 32768 + baseB;

#pragma unroll
        for (int q = 0; q < 4; ++q) {
            bf16x8 aF[2][2];
#pragma unroll
            for (int m2 = 0; m2 < 2; ++m2) {
                aF[m2][0] = *(const bf16x8*)(lds + sA + (q * 2 + m2) * 2048 + ax0);
                aF[m2][1] = *(const bf16x8*)(lds + sA + (q * 2 + m2) * 2048 + ax1);
            }
            if (q == 0) {
#pragma unroll
                for (int nf = 0; nf < 4; ++nf) {
                    bF[nf][0] = *(const bf16x8*)(lds + sB + nf * 2048 + ax0);
                    bF[nf][1] = *(const bf16x8*)(lds + sB + nf * 2048 + ax1);
                }
            }
            if (st) {
                if      (q == 0) { STB(sn, 0, 0, kn); STB(sn, 0, 1, kn); }
                else if (q == 1) { STB(sn, 1, 0, kn); STB(sn, 1, 1, kn); }
                else if (q == 2) { STA(sn, 0, 0, kn); STA(sn, 1, 0, kn); }
                else             { STA(sn, 0, 1, kn); STA(sn, 1, 1, kn); }
            }
            __builtin_amdgcn_s_barrier();
            __builtin_amdgcn_s_setprio(1);
#pragma unroll
            for (int m2 = 0; m2 < 2; ++m2)
#pragma unroll
                for (int nf = 0; nf < 4; ++nf)
#pragma unroll
                    for (int kk = 0; kk < 2; ++kk)
                        acc[q * 2 + m2][nf] = __builtin_amdgcn_mfma_f32_16x16x32_bf16(
                            aF[m2][kk], bF[nf][kk], acc[q * 2 + m2][nf], 0, 0, 0);
            __builtin_amdgcn_s_setprio(0);
            if (q == 1) { if (st) { WAITV(4); } else { WAITV(0); } }
            if (q == 3 && st) { WAITV(2); }
            __builtin_amdgcn_s_barrier();
        }
    }

    // epilogue: bias + elu(qk)+1, write bf16
    const bool isqk = (n0 < 2048);
    const int crow = (lane >> 4) * 4;
#pragma unroll
    for (int nf = 0; nf < 4; ++nf) {
        const int col = n0 + wn * 64 + nf * 16 + (lane & 15);
        const float bv = isqk ? b_qk[col] : b_v[col - 2048];
#pragma unroll
        for (int mf = 0; mf < 8; ++mf) {
            const int row0 = m0 + wm * 128 + mf * 16 + crow;
#pragma unroll
            for (int jj = 0; jj < 4; ++jj) {
                float vo = acc[mf][nf][jj] + bv;
                if (isqk) vo = vo > 0.f ? vo + 1.f : expf(vo);   // elu(x)+1
                Y[(size_t)(row0 + jj) * 3072 + col] = (bf16)vo;
            }
        }
    }
}
#undef STA
#undef STB
#undef WAITV

// ---------------- LePE (unchanged) ----------------
__global__ __launch_bounds__(256) void lepe(const bf16* __restrict__ Y,
                                            const float* __restrict__ wl,
                                            const float* __restrict__ bl,
                                            bf16* __restrict__ qf,
                                            bf16* __restrict__ kf) {
    const int bx = blockIdx.x;
    const int bh = bx >> 6, m = bx & 63;
    const int b = bh >> 4, h = bh & 15;
    const int isK = blockIdx.y;
    const bf16* slab = Y + (size_t)(b * 4096) * 3072 + isK * 1024 + h * 64;
    bf16* outp = (isK ? kf : qf) + (size_t)(b * 4096) * 1024 + h * 64;

    __shared__ bf16  Gs[64][72];
    __shared__ float Cs[64][65];
    __shared__ float ep[64], en[64];
    const int t = threadIdx.x;
    {
        const int d = t >> 2, c0 = (t & 3) * 16;
        const bf16* src = slab + (size_t)(d * 64 + m) * 3072 + c0;
        *(bf16x8*)&Gs[d][c0]     = *(const bf16x8*)src;
        *(bf16x8*)&Gs[d][c0 + 8] = *(const bf16x8*)(src + 8);
    }
    if (t < 64) {
        const int d = t;
        ep[d] = (m > 0)  ? (float)slab[(size_t)(d * 64 + m - 1) * 3072 + 63] : 0.f;
        en[d] = (m < 63) ? (float)slab[(size_t)(d * 64 + m + 1) * 3072 + 0]  : 0.f;
    }
    __syncthreads();
    {
        const int d = t >> 2, j0 = (t & 3) * 16;
        const float w0 = wl[d * 3], w1 = wl[d * 3 + 1], w2 = wl[d * 3 + 2], bb = bl[d];
#pragma unroll
        for (int jj = 0; jj < 16; ++jj) {
            const int j = j0 + jj;
            const float left  = (j == 0)  ? ep[d] : (float)Gs[d][j - 1];
            const float mid   = (float)Gs[d][j];
            const float right = (j == 63) ? en[d] : (float)Gs[d][j + 1];
            Cs[d][j] = w0 * left + w1 * mid + w2 * right + bb;
        }
    }
    __syncthreads();
    {
        const int j = t >> 2, c0 = (t & 3) * 16;
        const size_t l = (size_t)(m * 64 + j);
        const bf16* arow = slab + l * 3072 + c0;
        bf16* orow = outp + l * 1024 + c0;
        bf16x8 a0 = *(const bf16x8*)arow;
        bf16x8 a1 = *(const bf16x8*)(arow + 8);
        bf16x8 o0, o1;
#pragma unroll
        for (int i = 0; i < 8; ++i) {
            o0[i] = (bf16)((float)a0[i] + Cs[c0 + i][j]);
            o1[i] = (bf16)((float)a1[i] + Cs[c0 + 8 + i][j]);
        }
        *(bf16x8*)orow = o0;
        *(bf16x8*)(orow + 8) = o1;
    }
}

// ---------------- kv/ksum partials, register-blocked (unchanged) ----------------
__global__ __launch_bounds__(256) void kv_partial(const bf16* __restrict__ kf,
                                                  const bf16* __restrict__ Y,
                                                  float* __restrict__ kvp,
                                                  float* __restrict__ ksp) {
    const int bh = blockIdx.x, ch = blockIdx.y;
    const int b = bh >> 4, h = bh & 15;
    const bf16* K = kf + (size_t)(b * 4096) * 1024 + h * 64;
    const bf16* V = Y + (size_t)(b * 4096) * 3072 + 2048 + h * 64;

    __shared__ float SM[64 * 68 * 2 + 4 * 64];   // Ks | Vs | ksr
#define KS(r, c) SM[(r) * 68 + (c)]
#define VS(r, c) SM[4352 + (r) * 68 + (c)]
    float* ksr = SM + 8704;

    const int t = threadIdx.x;
    const int lane = t & 63;
    const int w = t >> 6;
    const int dg = lane >> 3, eg = lane & 7;

    f32x4 acc[8][2] = {};
    f32x4 ks0 = {}, ks1 = {};

    const int j = t >> 2, c0 = (t & 3) * 16;
    const int l0 = ch * 1024;
    const bf16* Kp = K + (size_t)(l0 + j) * 1024 + c0;
    const bf16* Vp = V + (size_t)(l0 + j) * 3072 + c0;
    bf16x8 k0 = *(const bf16x8*)Kp, k1 = *(const bf16x8*)(Kp + 8);
    bf16x8 v0 = *(const bf16x8*)Vp, v1 = *(const bf16x8*)(Vp + 8);

    for (int s = 0; s < 16; ++s) {
        __syncthreads();
        {
            f32x4 a, bx, c, d2;
#pragma unroll
            for (int i = 0; i < 4; ++i) { a[i] = (float)k0[i]; bx[i] = (float)k0[4 + i]; }
            *(f32x4*)&KS(j, c0) = a;  *(f32x4*)&KS(j, c0 + 4) = bx;
#pragma unroll
            for (int i = 0; i < 4; ++i) { c[i] = (float)k1[i]; d2[i] = (float)k1[4 + i]; }
            *(f32x4*)&KS(j, c0 + 8) = c; *(f32x4*)&KS(j, c0 + 12) = d2;
#pragma unroll
            for (int i = 0; i < 4; ++i) { a[i] = (float)v0[i]; bx[i] = (float)v0[4 + i]; }
            *(f32x4*)&VS(j, c0) = a;  *(f32x4*)&VS(j, c0 + 4) = bx;
#pragma unroll
            for (int i = 0; i < 4; ++i) { c[i] = (float)v1[i]; d2[i] = (float)v1[4 + i]; }
            *(f32x4*)&VS(j, c0 + 8) = c; *(f32x4*)&VS(j, c0 + 12) = d2;
        }
        __syncthreads();
        if (s < 15) {
            Kp += (size_t)64 * 1024; Vp += (size_t)64 * 3072;
            k0 = *(const bf16x8*)Kp; k1 = *(const bf16x8*)(Kp + 8);
            v0 = *(const bf16x8*)Vp; v1 = *(const bf16x8*)(Vp + 8);
        }
#pragma unroll
        for (int jj = 0; jj < 16; ++jj) {
            const int l = w * 16 + jj;
            f32x4 ka = *(const f32x4*)&KS(l, dg * 8);
            f32x4 kb = *(const f32x4*)&KS(l, dg * 8 + 4);
            f32x4 va = *(const f32x4*)&VS(l, eg * 8);
            f32x4 vb = *(const f32x4*)&VS(l, eg * 8 + 4);
            ks0 += ka; ks1 += kb;
#pragma unroll
            for (int i = 0; i < 4; ++i) {
                acc[i][0] += ka[i] * va;     acc[i][1] += ka[i] * vb;
                acc[4 + i][0] += kb[i] * va; acc[4 + i][1] += kb[i] * vb;
            }
        }
    }

    __syncthreads();
    if (eg == 0) {
#pragma unroll
        for (int i = 0; i < 4; ++i) {
            ksr[w * 64 + dg * 8 + i]     = ks0[i];
            ksr[w * 64 + dg * 8 + 4 + i] = ks1[i];
        }
    }
    if (w == 1 || w == 3) {
        float* buf = SM + (w >> 1) * 4352 + lane * 68;
#pragma unroll
        for (int i = 0; i < 8; ++i) {
            *(f32x4*)(buf + i * 8) = acc[i][0];
            *(f32x4*)(buf + i * 8 + 4) = acc[i][1];
        }
    }
    __syncthreads();
    if (w == 0 || w == 2) {
        float* buf = SM + (w >> 1) * 4352 + lane * 68;
#pragma unroll
        for (int i = 0; i < 8; ++i) {
            acc[i][0] += *(const f32x4*)(buf + i * 8);
            acc[i][1] += *(const f32x4*)(buf + i * 8 + 4);
        }
    }
    __syncthreads();
    if (w == 2) {
        float* buf = SM + lane * 68;
#pragma unroll
        for (int i = 0; i < 8; ++i) {
            *(f32x4*)(buf + i * 8) = acc[i][0];
            *(f32x4*)(buf + i * 8 + 4) = acc[i][1];
        }
    }
    __syncthreads();
    if (w == 0) {
        float* buf = SM + lane * 68;
#pragma unroll
        for (int i = 0; i < 8; ++i) {
            acc[i][0] += *(const f32x4*)(buf + i * 8);
            acc[i][1] += *(const f32x4*)(buf + i * 8 + 4);
        }
        float* o = kvp + (((size_t)ch * 64 + bh) * 64 + dg * 8) * 64 + eg * 8;
#pragma unroll
        for (int i = 0; i < 8; ++i) {
            *(f32x4*)(o + (size_t)i * 64)     = acc[i][0];
            *(f32x4*)(o + (size_t)i * 64 + 4) = acc[i][1];
        }
        if (eg == 0) {
#pragma unroll
            for (int i = 0; i < 8; ++i) {
                const int d = dg * 8 + i;
                ksp[(size_t)ch * 4096 + bh * 64 + d] =
                    ksr[d] + ksr[64 + d] + ksr[128 + d] + ksr[192 + d];
            }
        }
    }
#undef KS
#undef VS
}

// ---------------- out, register-blocked (unchanged) ----------------
__global__ __launch_bounds__(256) void out_kernel(const bf16* __restrict__ qf,
                                                  const float* __restrict__ kvp,
                                                  const float* __restrict__ ksp,
                                                  float* __restrict__ out) {
    const int bh = blockIdx.x;
    const int b = bh >> 4, h = bh & 15;
    __shared__ float kvS[4096];
    __shared__ float ksS[64];
    const int t = threadIdx.x;
    const float* kp = kvp + (size_t)bh * 4096;
#pragma unroll
    for (int i = 0; i < 4; ++i) {
        const int idx = i * 1024 + t * 4;
        f32x4 v = *(const f32x4*)(kp + idx);
        v = v + *(const f32x4*)(kp + 262144 + idx);
        v = v + *(const f32x4*)(kp + 524288 + idx);
        v = v + *(const f32x4*)(kp + 786432 + idx);
        *(f32x4*)(kvS + idx) = v;
    }
    if (t < 64) {
        ksS[t] = ksp[bh * 64 + t] + ksp[4096 + bh * 64 + t] +
                 ksp[8192 + bh * 64 + t] + ksp[12288 + bh * 64 + t];
    }
    __syncthreads();

    const int rg = t >> 2, eg = t & 3, e0 = eg * 16;
    const int r0 = blockIdx.y * 256 + rg * 4;
    const bf16* qbase = qf + (size_t)(b * 4096 + r0) * 1024 + h * 64;

    bf16x8 qv[4][8];
#pragma unroll
    for (int i = 0; i < 4; ++i)
#pragma unroll
        for (int s = 0; s < 8; ++s)
            qv[i][s] = *(const bf16x8*)(qbase + (size_t)i * 1024 + s * 8);

    float inv[4];
#pragma unroll
    for (int i = 0; i < 4; ++i) {
        float s = 0.f;
#pragma unroll
        for (int ss = 0; ss < 8; ++ss)
#pragma unroll
            for (int jj = 0; jj < 8; ++jj)
                s += (float)qv[i][ss][jj] * ksS[ss * 8 + jj];
        inv[i] = 1.0f / (s + 0.004096f);
    }

    f32x4 acc[4][4] = {};
#pragma unroll
    for (int d = 0; d < 64; ++d) {
        const float* kr = kvS + d * 64 + e0;
        f32x4 k0 = *(const f32x4*)kr;
        f32x4 k1 = *(const f32x4*)(kr + 4);
        f32x4 k2 = *(const f32x4*)(kr + 8);
        f32x4 k3 = *(const f32x4*)(kr + 12);
#pragma unroll
        for (int i = 0; i < 4; ++i) {
            const float qd = (float)qv[i][d >> 3][d & 7];
            acc[i][0] += qd * k0;
            acc[i][1] += qd * k1;
            acc[i][2] += qd * k2;
            acc[i][3] += qd * k3;
        }
    }
#pragma unroll
    for (int i = 0; i < 4; ++i) {
        float* orow = out + (size_t)(b * 4096 + r0 + i) * 1024 + h * 64 + e0;
#pragma unroll
        for (int q = 0; q < 4; ++q)
            *(f32x4*)(orow + q * 4) = acc[i][q] * inv[i];
    }
}

extern "C" void kernel_launch(void* const* d_in, const int* in_sizes, int n_in,
                              void* d_out, int out_size, void* d_ws, size_t ws_size,
                              hipStream_t stream) {
    const float* x      = (const float*)d_in[0];
    const float* w_qk   = (const float*)d_in[1];
    const float* b_qk   = (const float*)d_in[2];
    const float* w_v    = (const float*)d_in[3];
    const float* b_v    = (const float*)d_in[4];
    const float* w_lepe = (const float*)d_in[5];
    const float* b_lepe = (const float*)d_in[6];

    char* ws = (char*)d_ws;
    bf16*  Y   = (bf16*)ws;                       // 100,663,296
    bf16*  xb  = (bf16*)(ws + 100663296);         // 33,554,432 (qf after GEMM)
    bf16*  Wb  = (bf16*)(ws + 134217728);         // 33,554,432 (kf after GEMM)
    float* kvp = (float*)(ws + 167772160);        // 4,194,304
    float* ksp = (float*)(ws + 171966464);        // 65,536
    bf16* qf = xb;
    bf16* kf = Wb;

    cvt_f32_bf16<<<2048, 256, 0, stream>>>(x, xb, 16777216 / 4);
    cvt_f32_bf16<<<512,  256, 0, stream>>>(w_qk, Wb, 2097152 / 4);
    cvt_f32_bf16<<<256,  256, 0, stream>>>(w_v, Wb + 2097152, 1048576 / 4);
    gemm_qkv<<<768, 512, 0, stream>>>(xb, Wb, b_qk, b_v, Y);
    lepe<<<dim3(4096, 2), 256, 0, stream>>>(Y, w_lepe, b_lepe, qf, kf);
    kv_partial<<<dim3(64, 4), 256, 0, stream>>>(kf, Y, kvp, ksp);
    out_kernel<<<dim3(64, 16), 256, 0, stream>>>(qf, kvp, ksp, (float*)d_out);
}